// Round 9
// baseline (159.976 us; speedup 1.0000x reference)
//
#include <hip/hip_runtime.h>
#include <hip/hip_bf16.h>
#include <stdint.h>

typedef __attribute__((ext_vector_type(4))) int i32x4;

static constexpr long M_ = 16384;   // 4*4096 rows of x
static constexpr long N_ = 2048;    // out_features
static constexpr long K_ = 2048;    // in_features

// ---- 128x128 i8 GEMM, 4 blocks/CU, 4 waves/SIMD ----
// 4 waves (2m x 2n), 256 threads, wave tile 64x64 (acc = 64 VGPR), BK=64.
// Static LDS 32 KB (A[2][128][64] + B[2][128][64]) -> 4 blocks/CU; with
// <=128 VGPR -> 16 waves/CU = 4 waves/SIMD. Four blocks share NO barriers,
// so one block's LDS window overlaps another's MFMA window (m114 mechanism).
// Staging decomposition (r8 bugfix): wave w covers rows w*32..w*32+31 via
// two gloads at +0 and +16 rows (LDS +0, +1024) -- r7 stageA geometry.
// Swizzle: row r, logical 16B-chunk c stored at physical chunk c ^ ((r>>1)&3).

#define GLOAD_LDS16(g, l)                                                          \
  __builtin_amdgcn_global_load_lds(                                               \
      (const __attribute__((address_space(1))) unsigned int*)(g),                 \
      (__attribute__((address_space(3))) unsigned int*)(l), 16, 0, 0)

// ---------------- fused stats: max|x| (blocks 0..2047), sum|W| (2048..2559) ----
__global__ __launch_bounds__(256) void k_stats(const float4* __restrict__ x,
                                               const float4* __restrict__ w,
                                               unsigned* __restrict__ gx_bits,
                                               double* __restrict__ gw_sum) {
  const int b = blockIdx.x;
  const int lane = threadIdx.x & 63, wv = threadIdx.x >> 6;
  if (b < 2048) {
    const long S = 524288;
    long i = (long)b * 256 + threadIdx.x;
    float m0 = 0.f, m1 = 0.f, m2 = 0.f, m3 = 0.f;
#pragma unroll
    for (int it = 0; it < 4; ++it) {
      float4 v0 = x[i];
      float4 v1 = x[i + S];
      float4 v2 = x[i + 2 * S];
      float4 v3 = x[i + 3 * S];
      m0 = fmaxf(m0, fmaxf(fmaxf(fabsf(v0.x), fabsf(v0.y)), fmaxf(fabsf(v0.z), fabsf(v0.w))));
      m1 = fmaxf(m1, fmaxf(fmaxf(fabsf(v1.x), fabsf(v1.y)), fmaxf(fabsf(v1.z), fabsf(v1.w))));
      m2 = fmaxf(m2, fmaxf(fmaxf(fabsf(v2.x), fabsf(v2.y)), fmaxf(fabsf(v2.z), fabsf(v2.w))));
      m3 = fmaxf(m3, fmaxf(fmaxf(fabsf(v3.x), fabsf(v3.y)), fmaxf(fabsf(v3.z), fabsf(v3.w))));
      i += 4 * S;
    }
    float m = fmaxf(fmaxf(m0, m1), fmaxf(m2, m3));
#pragma unroll
    for (int off = 32; off > 0; off >>= 1) m = fmaxf(m, __shfl_down(m, off));
    __shared__ float sm[4];
    if (lane == 0) sm[wv] = m;
    __syncthreads();
    if (threadIdx.x == 0) {
      float bm = fmaxf(fmaxf(sm[0], sm[1]), fmaxf(sm[2], sm[3]));
      atomicMax(gx_bits, __float_as_uint(bm));  // all >= 0
    }
  } else {
    const long S = 131072;
    long i = (long)(b - 2048) * 256 + threadIdx.x;
    double s = 0.0;
#pragma unroll
    for (int it = 0; it < 8; ++it) {
      float4 v = w[i];
      s += (double)fabsf(v.x) + (double)fabsf(v.y) + (double)fabsf(v.z) + (double)fabsf(v.w);
      i += S;
    }
#pragma unroll
    for (int off = 32; off > 0; off >>= 1) s += __shfl_down(s, off);
    __shared__ double sd[4];
    if (lane == 0) sd[wv] = s;
    __syncthreads();
    if (threadIdx.x == 0) atomicAdd(gw_sum, (sd[0] + sd[1]) + (sd[2] + sd[3]));
  }
}

// ---------------- fused quant: x (blocks 0..2047), W (2048..2559) ----------------
__global__ __launch_bounds__(256) void k_quant(const float4* __restrict__ x,
                                               const float4* __restrict__ w,
                                               char4* __restrict__ xq,
                                               char4* __restrict__ wq,
                                               const unsigned* __restrict__ gx_bits,
                                               const double* __restrict__ gw_sum) {
  const int b = blockIdx.x;
  if (b < 2048) {
    const double gx = (double)fmaxf(__uint_as_float(*gx_bits), 1e-8f);
    const double scale = 127.0 / gx;
    const long S = 524288;
    long i = (long)b * 256 + threadIdx.x;
#pragma unroll
    for (int it = 0; it < 16; ++it) {
      float4 v = x[i];
      char4 o;
      o.x = (signed char)(int)fmin(fmax(rint((double)v.x * scale), -127.0), 127.0);
      o.y = (signed char)(int)fmin(fmax(rint((double)v.y * scale), -127.0), 127.0);
      o.z = (signed char)(int)fmin(fmax(rint((double)v.z * scale), -127.0), 127.0);
      o.w = (signed char)(int)fmin(fmax(rint((double)v.w * scale), -127.0), 127.0);
      xq[i] = o;
      i += S;
    }
  } else {
    const double gw = fmax(*gw_sum * (1.0 / 4194304.0), 1e-8);
    const double inv = 1.0 / gw;
    const long S = 131072;
    long i = (long)(b - 2048) * 256 + threadIdx.x;
#pragma unroll
    for (int it = 0; it < 8; ++it) {
      float4 v = w[i];
      char4 o;
      o.x = (signed char)(int)fmin(fmax(rint((double)v.x * inv), -1.0), 1.0);
      o.y = (signed char)(int)fmin(fmax(rint((double)v.y * inv), -1.0), 1.0);
      o.z = (signed char)(int)fmin(fmax(rint((double)v.z * inv), -1.0), 1.0);
      o.w = (signed char)(int)fmin(fmax(rint((double)v.w * inv), -1.0), 1.0);
      wq[i] = o;
      i += S;
    }
  }
}

// ================= GEMM =================
// LDS: A buf0 @0, A buf1 @8192, B buf0 @16384, B buf1 @24576 (8 KB regions).

template <int ISB, int BUF>
__device__ __forceinline__ void stage(signed char* lds, const signed char* gp, int kb,
                                      int go0, int wslot) {
  constexpr int R = ISB * 16384 + BUF * 8192;
  GLOAD_LDS16(gp + kb + go0, lds + R + wslot);
  GLOAD_LDS16(gp + kb + go0 + 16 * 2048, lds + R + wslot + 1024);
}

template <int C>
__device__ __forceinline__ void kstep(signed char* lds, const signed char* Ap,
                                      const signed char* Bp, int kb,
                                      const signed char* pA, const signed char* pB,
                                      int go0, int wslot, i32x4 acc[4][4]) {
  constexpr int RA = C * 8192;
  constexpr int RB = 16384 + C * 8192;
  i32x4 a4[4], b4[4];
#pragma unroll
  for (int n = 0; n < 4; ++n) b4[n] = *(const i32x4*)(pB + RB + n * 1024);
#pragma unroll
  for (int m = 0; m < 4; ++m) a4[m] = *(const i32x4*)(pA + RA + m * 1024);

  stage<0, C ^ 1>(lds, Ap, kb, go0, wslot);
  stage<1, C ^ 1>(lds, Bp, kb, go0, wslot);

  asm volatile("s_waitcnt lgkmcnt(0)" ::: "memory");
  __builtin_amdgcn_sched_barrier(0);
  __builtin_amdgcn_s_setprio(1);
#pragma unroll
  for (int m = 0; m < 4; ++m)
#pragma unroll
    for (int n = 0; n < 4; ++n)
      acc[m][n] = __builtin_amdgcn_mfma_i32_16x16x64_i8(a4[m], b4[n], acc[m][n], 0, 0, 0);
  __builtin_amdgcn_s_setprio(0);
  asm volatile("s_waitcnt vmcnt(0)" ::: "memory");
  __builtin_amdgcn_s_barrier();  // publish buf C^1
}

__global__ __launch_bounds__(256, 4) void k_gemm(
    const signed char* __restrict__ Aq, const signed char* __restrict__ Bq,
    const float* __restrict__ bias, float* __restrict__ out,
    const unsigned* __restrict__ gx_bits, const double* __restrict__ gw_sum) {
  __shared__ signed char lds[32768];

  const int tid = threadIdx.x;
  const int lane = tid & 63;
  const int wid = tid >> 6;       // 0..3
  const int wave_m = wid >> 1;    // 0..1
  const int wave_n = wid & 1;     // 0..1
  const int l15 = lane & 15;

  // XCD swizzle: nwg = 2048, 8 XCDs, 256 contiguous work-ids per XCD;
  // 16 consecutive wg share one A-panel (all nblk values) -> A L2 reuse.
  const int wg = (int)((blockIdx.x & 7) * 256 + (blockIdx.x >> 3));
  const int nblk = wg & 15;  // N_/128 = 16
  const int mblk = wg >> 4;  // 0..127
  const long brow = (long)mblk * 128;
  const long bcol = (long)nblk * 128;

  const signed char* Ap = Aq + brow * K_;
  const signed char* Bp = Bq + bcol * K_;

  // LDS read bases; all row bases are multiples of 16 -> swizzle term
  // depends only on lane&15
  const int swz = ((lane >> 4) ^ ((l15 >> 1) & 3)) << 4;
  const signed char* pA = lds + (wave_m * 64 + l15) * 64 + swz;
  const signed char* pB = lds + (wave_n * 64 + l15) * 64 + swz;

  // stage offsets: wave w covers rows w*32..w*32+31 (two 16-row gloads);
  // logical chunk c0 = (lane&3)^((lane>>3)&3) (pre-swizzled global source)
  const int c0 = (lane & 3) ^ ((lane >> 3) & 3);
  const int go0 = (wid * 32 + (lane >> 2)) * (int)K_ + c0 * 16;
  const int wslot = wid * 2048;

  i32x4 acc[4][4];
#pragma unroll
  for (int m = 0; m < 4; m++)
#pragma unroll
    for (int n = 0; n < 4; n++) acc[m][n] = (i32x4){0, 0, 0, 0};

  // prologue: stage kstep 0 into buf0
  stage<0, 0>(lds, Ap, 0, go0, wslot);
  stage<1, 0>(lds, Bp, 0, go0, wslot);
  asm volatile("s_waitcnt vmcnt(0)" ::: "memory");
  __builtin_amdgcn_s_barrier();

  for (int kt = 0; kt < (int)K_; kt += 128) {
    kstep<0>(lds, Ap, Bp, kt + 64, pA, pB, go0, wslot, acc);
    kstep<1>(lds, Ap, Bp, (kt + 128) & 2047, pA, pB, go0, wslot, acc);
  }

  const float gxf = fmaxf(__uint_as_float(*gx_bits), 1e-8f);
  const double gwd = fmax(*gw_sum * (1.0 / 4194304.0), 1e-8);
  const float alpha = (float)((double)gxf * gwd * (1.0 / 127.0));

#pragma unroll
  for (int n = 0; n < 4; ++n) {
    const long col = bcol + wave_n * 64 + n * 16 + l15;
    const float bv = bias[col];
#pragma unroll
    for (int m = 0; m < 4; ++m) {
      const long row0 = brow + wave_m * 64 + m * 16 + (lane >> 4) * 4;
#pragma unroll
      for (int r = 0; r < 4; ++r) {
        out[(row0 + r) * N_ + col] = (float)acc[m][n][r] * alpha + bv;
      }
    }
  }
}

extern "C" void kernel_launch(void* const* d_in, const int* in_sizes, int n_in,
                              void* d_out, int out_size, void* d_ws, size_t ws_size,
                              hipStream_t stream) {
  const float* x = (const float*)d_in[0];
  const float* W = (const float*)d_in[1];
  const float* b = (const float*)d_in[2];
  float* out = (float*)d_out;

  char* ws = (char*)d_ws;
  double* gw_sum = (double*)ws;            // 8 B
  unsigned* gx_bits = (unsigned*)(ws + 8); // 4 B
  signed char* xq = (signed char*)(ws + 256);                            // M*K i8 = 32 MiB
  signed char* wq = (signed char*)(ws + 256 + (size_t)M_ * (size_t)K_);  // N*K i8 = 4 MiB

  hipMemsetAsync(ws, 0, 16, stream);
  hipLaunchKernelGGL(k_stats, dim3(2560), dim3(256), 0, stream,
                     (const float4*)x, (const float4*)W, gx_bits, gw_sum);
  hipLaunchKernelGGL(k_quant, dim3(2560), dim3(256), 0, stream,
                     (const float4*)x, (const float4*)W, (char4*)xq, (char4*)wq,
                     gx_bits, gw_sum);
  hipLaunchKernelGGL(k_gemm, dim3((unsigned)((M_ / 128) * (N_ / 128))), dim3(256),
                     0, stream, xq, wq, b, out, gx_bits, gw_sum);
}

// Round 10
// 155.907 us; speedup vs baseline: 1.0261x; 1.0261x over previous
//
#include <hip/hip_runtime.h>
#include <hip/hip_bf16.h>
#include <stdint.h>

typedef __attribute__((ext_vector_type(4))) int i32x4;

static constexpr long M_ = 16384;   // 4*4096 rows of x
static constexpr long N_ = 2048;    // out_features
static constexpr long K_ = 2048;    // in_features

// ---- 256x256 i8 GEMM, 8 phases/iter, REGISTER-PIPELINED fragments ----
// 8 waves (2M x 4N), 512 threads, BK=128 i8, LDS 128 KiB (4 regions x A,B).
// KEY CHANGE vs r4-r9: phase p's ds_reads load the frags for phase p+1
// (ping-pong reg sets); MFMA p consumes frags loaded at p-1. The LDS port
// serves p+1's reads WHILE the MFMA pipe drains p -- overlap by dataflow
// construction (all prior variants waited lgkmcnt(0) on same-phase reads,
// serializing the ~580cy LDS window against the ~590cy MFMA window; that
// sum is the 1600cy/phase invariant measured r3-r9).
// Staging map unchanged from r4; vmcnt deepened 8->4 so every region is
// formally complete >=1 phase before its (now one-earlier) first read.
// Swizzle: row r, logical 16B-chunk c at physical chunk c ^ ((r>>1)&3).

#define GLOAD_LDS16(g, l)                                                          \
  __builtin_amdgcn_global_load_lds(                                               \
      (const __attribute__((address_space(1))) unsigned int*)(g),                 \
      (__attribute__((address_space(3))) unsigned int*)(l), 16, 0, 0)

// ---------------- fused stats: max|x| (blocks 0..2047), sum|W| (2048..2559) ----
__global__ __launch_bounds__(256) void k_stats(const float4* __restrict__ x,
                                               const float4* __restrict__ w,
                                               unsigned* __restrict__ gx_bits,
                                               double* __restrict__ gw_sum) {
  const int b = blockIdx.x;
  const int lane = threadIdx.x & 63, wv = threadIdx.x >> 6;
  if (b < 2048) {
    const long S = 524288;
    long i = (long)b * 256 + threadIdx.x;
    float m0 = 0.f, m1 = 0.f, m2 = 0.f, m3 = 0.f;
#pragma unroll
    for (int it = 0; it < 4; ++it) {
      float4 v0 = x[i];
      float4 v1 = x[i + S];
      float4 v2 = x[i + 2 * S];
      float4 v3 = x[i + 3 * S];
      m0 = fmaxf(m0, fmaxf(fmaxf(fabsf(v0.x), fabsf(v0.y)), fmaxf(fabsf(v0.z), fabsf(v0.w))));
      m1 = fmaxf(m1, fmaxf(fmaxf(fabsf(v1.x), fabsf(v1.y)), fmaxf(fabsf(v1.z), fabsf(v1.w))));
      m2 = fmaxf(m2, fmaxf(fmaxf(fabsf(v2.x), fabsf(v2.y)), fmaxf(fabsf(v2.z), fabsf(v2.w))));
      m3 = fmaxf(m3, fmaxf(fmaxf(fabsf(v3.x), fabsf(v3.y)), fmaxf(fabsf(v3.z), fabsf(v3.w))));
      i += 4 * S;
    }
    float m = fmaxf(fmaxf(m0, m1), fmaxf(m2, m3));
#pragma unroll
    for (int off = 32; off > 0; off >>= 1) m = fmaxf(m, __shfl_down(m, off));
    __shared__ float sm[4];
    if (lane == 0) sm[wv] = m;
    __syncthreads();
    if (threadIdx.x == 0) {
      float bm = fmaxf(fmaxf(sm[0], sm[1]), fmaxf(sm[2], sm[3]));
      atomicMax(gx_bits, __float_as_uint(bm));  // all >= 0
    }
  } else {
    const long S = 131072;
    long i = (long)(b - 2048) * 256 + threadIdx.x;
    double s = 0.0;
#pragma unroll
    for (int it = 0; it < 8; ++it) {
      float4 v = w[i];
      s += (double)fabsf(v.x) + (double)fabsf(v.y) + (double)fabsf(v.z) + (double)fabsf(v.w);
      i += S;
    }
#pragma unroll
    for (int off = 32; off > 0; off >>= 1) s += __shfl_down(s, off);
    __shared__ double sd[4];
    if (lane == 0) sd[wv] = s;
    __syncthreads();
    if (threadIdx.x == 0) atomicAdd(gw_sum, (sd[0] + sd[1]) + (sd[2] + sd[3]));
  }
}

// ---------------- fused quant: x (blocks 0..2047), W (2048..2559) ----------------
__global__ __launch_bounds__(256) void k_quant(const float4* __restrict__ x,
                                               const float4* __restrict__ w,
                                               char4* __restrict__ xq,
                                               char4* __restrict__ wq,
                                               const unsigned* __restrict__ gx_bits,
                                               const double* __restrict__ gw_sum) {
  const int b = blockIdx.x;
  if (b < 2048) {
    const double gx = (double)fmaxf(__uint_as_float(*gx_bits), 1e-8f);
    const double scale = 127.0 / gx;
    const long S = 524288;
    long i = (long)b * 256 + threadIdx.x;
#pragma unroll
    for (int it = 0; it < 16; ++it) {
      float4 v = x[i];
      char4 o;
      o.x = (signed char)(int)fmin(fmax(rint((double)v.x * scale), -127.0), 127.0);
      o.y = (signed char)(int)fmin(fmax(rint((double)v.y * scale), -127.0), 127.0);
      o.z = (signed char)(int)fmin(fmax(rint((double)v.z * scale), -127.0), 127.0);
      o.w = (signed char)(int)fmin(fmax(rint((double)v.w * scale), -127.0), 127.0);
      xq[i] = o;
      i += S;
    }
  } else {
    const double gw = fmax(*gw_sum * (1.0 / 4194304.0), 1e-8);
    const double inv = 1.0 / gw;
    const long S = 131072;
    long i = (long)(b - 2048) * 256 + threadIdx.x;
#pragma unroll
    for (int it = 0; it < 8; ++it) {
      float4 v = w[i];
      char4 o;
      o.x = (signed char)(int)fmin(fmax(rint((double)v.x * inv), -1.0), 1.0);
      o.y = (signed char)(int)fmin(fmax(rint((double)v.y * inv), -1.0), 1.0);
      o.z = (signed char)(int)fmin(fmax(rint((double)v.z * inv), -1.0), 1.0);
      o.w = (signed char)(int)fmin(fmax(rint((double)v.w * inv), -1.0), 1.0);
      wq[i] = o;
      i += S;
    }
  }
}

// ================= pipelined 8-phase GEMM =================
// Regions (A): offset = BUF*32768 + KS*16384; B at +65536.
// Phase p (0..7): region(p) = (BUF=p>>2, KS=(p>>1)&1), MH = p&1.
// Stage map: pair (p>>1) stages region ((p>>1)+3)&3: A at even p, B at odd p.
// kb per pair: kt+192, kt+256, kt+320, kt+384.

template <int P>
__device__ __forceinline__ void phaseP(signed char* lds, const signed char* Ap,
                                       const signed char* Bp, int kb,
                                       const signed char* pA, const signed char* pB,
                                       int go0, int ldsl0, i32x4 (&aS)[2][4],
                                       i32x4 (&bS)[2][4], i32x4 (&acc)[8][4]) {
  constexpr int Q = (P + 1) & 7;
  constexpr int QR = ((Q >> 2) & 1) * 32768 + ((Q >> 1) & 1) * 16384;
  constexpr int QMH = Q & 1;
  // --- issue ds_reads for phase P+1 (ping-pong reg sets) ---
#pragma unroll
  for (int m = 0; m < 4; ++m)
    aS[Q & 1][m] = *(const i32x4*)(pA + QR + QMH * 4096 + m * 1024);
  if constexpr (QMH == 0) {
#pragma unroll
    for (int n = 0; n < 4; ++n)
      bS[(Q >> 1) & 1][n] = *(const i32x4*)(pB + QR + n * 1024);
  }
  __builtin_amdgcn_sched_barrier(0);
  // --- stage one quarter of a future region ---
  constexpr int SREG = ((P >> 1) + 3) & 3;
  constexpr int SOFF = ((SREG >> 1) & 1) * 32768 + (SREG & 1) * 16384;
  if constexpr ((P & 1) == 0) {
    GLOAD_LDS16(Ap + kb + go0, lds + SOFF + ldsl0);
    GLOAD_LDS16(Ap + kb + go0 + 32768, lds + SOFF + ldsl0 + 1024);
  } else {
    GLOAD_LDS16(Bp + kb + go0, lds + 65536 + SOFF + ldsl0);
    GLOAD_LDS16(Bp + kb + go0 + 32768, lds + 65536 + SOFF + ldsl0 + 1024);
  }
  __builtin_amdgcn_sched_barrier(0);
  // --- MFMA on frags loaded LAST phase (LDS port serves new reads now) ---
  __builtin_amdgcn_s_setprio(1);
#pragma unroll
  for (int m = 0; m < 4; ++m)
#pragma unroll
    for (int n = 0; n < 4; ++n)
      acc[(P & 1) * 4 + m][n] = __builtin_amdgcn_mfma_i32_16x16x64_i8(
          aS[P & 1][m], bS[(P >> 1) & 1][n], acc[(P & 1) * 4 + m][n], 0, 0, 0);
  __builtin_amdgcn_s_setprio(0);
  asm volatile("s_waitcnt lgkmcnt(0)" ::: "memory");
  __builtin_amdgcn_sched_barrier(0);
  if constexpr ((P & 1) == 1) asm volatile("s_waitcnt vmcnt(4)" ::: "memory");
  __builtin_amdgcn_s_barrier();
}

__global__ __launch_bounds__(512, 2) void k_gemm(
    const signed char* __restrict__ Aq, const signed char* __restrict__ Bq,
    const float* __restrict__ bias, float* __restrict__ out,
    const unsigned* __restrict__ gx_bits, const double* __restrict__ gw_sum) {
  extern __shared__ signed char lds[];

  const int tid = threadIdx.x;
  const int lane = tid & 63;
  const int wid = tid >> 6;
  const int wave_m = wid >> 2;  // 0..1
  const int wave_n = wid & 3;   // 0..3
  const int l15 = lane & 15;

  // XCD swizzle: nwg = 512, 8 XCDs, 64 contiguous work-ids per XCD
  const int wg = (int)((blockIdx.x & 7) * 64 + (blockIdx.x >> 3));
  const int nblk = wg & 7;   // N_/256 = 8
  const int mblk = wg >> 3;  // 0..63
  const long brow = (long)mblk * 256;
  const long bcol = (long)nblk * 256;

  const signed char* Ap = Aq + brow * K_;
  const signed char* Bp = Bq + bcol * K_;

  // LDS read bases (per-thread constants); row bases are multiples of 16
  const int swz = ((lane >> 4) ^ ((l15 >> 1) & 3)) << 4;
  const signed char* pA = lds + (wave_m * 128 + l15) * 64 + swz;
  const signed char* pB = lds + 65536 + (wave_n * 64 + l15) * 64 + swz;

  // stage offsets: wave w rows w*32..w*32+31; chunk c0 pre-swizzled
  const int c0 = (lane & 3) ^ ((lane >> 3) & 3);
  const int go0 = (wid * 32 + (lane >> 2)) * (int)K_ + c0 * 16;
  const int ldsl0 = wid * 2048;

  i32x4 acc[8][4];
#pragma unroll
  for (int m = 0; m < 8; m++)
#pragma unroll
    for (int n = 0; n < 4; n++) acc[m][n] = (i32x4){0, 0, 0, 0};
  i32x4 aS[2][4], bS[2][4];

  // prologue: stage regions (0,0)@k0, (0,1)@k64, (1,0)@k128
  GLOAD_LDS16(Ap + go0, lds + ldsl0);
  GLOAD_LDS16(Ap + go0 + 32768, lds + ldsl0 + 1024);
  GLOAD_LDS16(Bp + go0, lds + 65536 + ldsl0);
  GLOAD_LDS16(Bp + go0 + 32768, lds + 65536 + ldsl0 + 1024);
  GLOAD_LDS16(Ap + 64 + go0, lds + 16384 + ldsl0);
  GLOAD_LDS16(Ap + 64 + go0 + 32768, lds + 16384 + ldsl0 + 1024);
  GLOAD_LDS16(Bp + 64 + go0, lds + 65536 + 16384 + ldsl0);
  GLOAD_LDS16(Bp + 64 + go0 + 32768, lds + 65536 + 16384 + ldsl0 + 1024);
  GLOAD_LDS16(Ap + 128 + go0, lds + 32768 + ldsl0);
  GLOAD_LDS16(Ap + 128 + go0 + 32768, lds + 32768 + ldsl0 + 1024);
  GLOAD_LDS16(Bp + 128 + go0, lds + 65536 + 32768 + ldsl0);
  GLOAD_LDS16(Bp + 128 + go0 + 32768, lds + 65536 + 32768 + ldsl0 + 1024);
  asm volatile("s_waitcnt vmcnt(0)" ::: "memory");
  __builtin_amdgcn_s_barrier();

  // preload frags for phase 0 (region (0,0), MH0)
#pragma unroll
  for (int n = 0; n < 4; ++n) bS[0][n] = *(const i32x4*)(pB + n * 1024);
#pragma unroll
  for (int m = 0; m < 4; ++m) aS[0][m] = *(const i32x4*)(pA + m * 1024);
  asm volatile("s_waitcnt lgkmcnt(0)" ::: "memory");
  __builtin_amdgcn_sched_barrier(0);

  for (int kt = 0; kt < (int)K_; kt += 256) {
    const int c0k = (kt + 192) & 2047;
    const int c1k = (kt + 256) & 2047;
    const int c2k = (kt + 320) & 2047;
    const int c3k = (kt + 384) & 2047;
    phaseP<0>(lds, Ap, Bp, c0k, pA, pB, go0, ldsl0, aS, bS, acc);
    phaseP<1>(lds, Ap, Bp, c0k, pA, pB, go0, ldsl0, aS, bS, acc);
    phaseP<2>(lds, Ap, Bp, c1k, pA, pB, go0, ldsl0, aS, bS, acc);
    phaseP<3>(lds, Ap, Bp, c1k, pA, pB, go0, ldsl0, aS, bS, acc);
    phaseP<4>(lds, Ap, Bp, c2k, pA, pB, go0, ldsl0, aS, bS, acc);
    phaseP<5>(lds, Ap, Bp, c2k, pA, pB, go0, ldsl0, aS, bS, acc);
    phaseP<6>(lds, Ap, Bp, c3k, pA, pB, go0, ldsl0, aS, bS, acc);
    phaseP<7>(lds, Ap, Bp, c3k, pA, pB, go0, ldsl0, aS, bS, acc);
  }

  const float gxf = fmaxf(__uint_as_float(*gx_bits), 1e-8f);
  const double gwd = fmax(*gw_sum * (1.0 / 4194304.0), 1e-8);
  const float alpha = (float)((double)gxf * gwd * (1.0 / 127.0));

#pragma unroll
  for (int n = 0; n < 4; ++n) {
    const long col = bcol + wave_n * 64 + n * 16 + l15;
    const float bv = bias[col];
#pragma unroll
    for (int m = 0; m < 8; ++m) {
      const long row0 = brow + wave_m * 128 + m * 16 + (lane >> 4) * 4;
#pragma unroll
      for (int r = 0; r < 4; ++r) {
        out[(row0 + r) * N_ + col] = (float)acc[m][n][r] * alpha + bv;
      }
    }
  }
}

extern "C" void kernel_launch(void* const* d_in, const int* in_sizes, int n_in,
                              void* d_out, int out_size, void* d_ws, size_t ws_size,
                              hipStream_t stream) {
  const float* x = (const float*)d_in[0];
  const float* W = (const float*)d_in[1];
  const float* b = (const float*)d_in[2];
  float* out = (float*)d_out;

  char* ws = (char*)d_ws;
  double* gw_sum = (double*)ws;            // 8 B
  unsigned* gx_bits = (unsigned*)(ws + 8); // 4 B
  signed char* xq = (signed char*)(ws + 256);                            // M*K i8 = 32 MiB
  signed char* wq = (signed char*)(ws + 256 + (size_t)M_ * (size_t)K_);  // N*K i8 = 4 MiB

  static bool attr_set = false;
  if (!attr_set) {
    (void)hipFuncSetAttribute(reinterpret_cast<const void*>(&k_gemm),
                              hipFuncAttributeMaxDynamicSharedMemorySize, 131072);
    attr_set = true;
  }

  hipMemsetAsync(ws, 0, 16, stream);
  hipLaunchKernelGGL(k_stats, dim3(2560), dim3(256), 0, stream,
                     (const float4*)x, (const float4*)W, gx_bits, gw_sum);
  hipLaunchKernelGGL(k_quant, dim3(2560), dim3(256), 0, stream,
                     (const float4*)x, (const float4*)W, (char4*)xq, (char4*)wq,
                     gx_bits, gw_sum);
  hipLaunchKernelGGL(k_gemm, dim3((unsigned)((M_ / 256) * (N_ / 256))), dim3(512),
                     131072, stream, xq, wq, b, out, gx_bits, gw_sum);
}